// Round 1
// baseline (356.472 us; speedup 1.0000x reference)
//
#include <hip/hip_runtime.h>

#define N_RAYS 16384
#define MAX_STEPS 512
#define GRID_R 128
#define NS (N_RAYS * MAX_STEPS) /* 8388608 samples */

// ---------------------------------------------------------------------------
// Kernel 0: detect occ_grid storage dtype (bool marshalling is ambiguous).
// mode 0 = int32 words (0/1), mode 1 = float32 (0.0/1.0), mode 2 = uint8.
// ---------------------------------------------------------------------------
__global__ void detect_dtype(const void* __restrict__ occ, int* __restrict__ flag) {
    __shared__ int ok_int, ok_flt;
    if (threadIdx.x == 0) { ok_int = 1; ok_flt = 1; }
    __syncthreads();
    const int*   pi = (const int*)occ;
    const float* pf = (const float*)occ;
    for (int i = threadIdx.x; i < 1024; i += blockDim.x) {
        int v = pi[i];
        if (v != 0 && v != 1) atomicAnd(&ok_int, 0);
        float f = pf[i];
        if (!(f == 0.0f || f == 1.0f)) atomicAnd(&ok_flt, 0);
    }
    __syncthreads();
    if (threadIdx.x == 0) flag[0] = ok_int ? 0 : (ok_flt ? 1 : 2);
}

// ---------------------------------------------------------------------------
// Kernel 1: one block per ray, one thread per step.
// Writes origins/dirs/s/e/ray_indices/mask for every (ray,step); reduces
// per-ray valid count into counts[ray].
// All mul+add chains that feed comparisons use _rn intrinsics so the
// compiler cannot contract them into FMA (numpy reference has no FMA).
// ---------------------------------------------------------------------------
__global__ __launch_bounds__(512)
void sample_kernel(const float* __restrict__ rays_o, const float* __restrict__ rays_d,
                   const float* __restrict__ aabb, const void* __restrict__ occ,
                   const int* __restrict__ flag_p, float* __restrict__ out,
                   int* __restrict__ counts)
{
    const int r = blockIdx.x;
    const int s = threadIdx.x;
    const int mode = flag_p[0];

    const float ox = rays_o[3 * r + 0], oy = rays_o[3 * r + 1], oz = rays_o[3 * r + 2];
    const float dx = rays_d[3 * r + 0], dy = rays_d[3 * r + 1], dz = rays_d[3 * r + 2];
    const float a0x = aabb[0], a0y = aabb[1], a0z = aabb[2];
    const float a1x = aabb[3], a1y = aabb[4], a1z = aabb[5];

    // safe_d = where(|d| > 1e-10, d, 1e-10); inv = 1/safe_d (IEEE divide)
    const float sdx = (fabsf(dx) > 1e-10f) ? dx : 1e-10f;
    const float sdy = (fabsf(dy) > 1e-10f) ? dy : 1e-10f;
    const float sdz = (fabsf(dz) > 1e-10f) ? dz : 1e-10f;
    const float invx = __fdiv_rn(1.0f, sdx);
    const float invy = __fdiv_rn(1.0f, sdy);
    const float invz = __fdiv_rn(1.0f, sdz);

    const float t0x = __fmul_rn(__fsub_rn(a0x, ox), invx);
    const float t1x = __fmul_rn(__fsub_rn(a1x, ox), invx);
    const float t0y = __fmul_rn(__fsub_rn(a0y, oy), invy);
    const float t1y = __fmul_rn(__fsub_rn(a1y, oy), invy);
    const float t0z = __fmul_rn(__fsub_rn(a0z, oz), invz);
    const float t1z = __fmul_rn(__fsub_rn(a1z, oz), invz);

    const float tmin = fmaxf(fmaxf(fmaxf(fminf(t0x, t1x), fminf(t0y, t1y)), fminf(t0z, t1z)), 0.05f);
    const float tmax = fminf(fminf(fminf(fmaxf(t0x, t1x), fmaxf(t0y, t1y)), fmaxf(t0z, t1z)), 3.0f);

    // edges = NEAR + arange*STEP, STEP cast from double like JAX weak promotion
    const float step_f = (float)((3.0 - 0.05) / 512.0);
    const float start = __fadd_rn(0.05f, __fmul_rn((float)s, step_f));
    const float end   = __fadd_rn(0.05f, __fmul_rn((float)(s + 1), step_f));
    const float mid   = __fmul_rn(0.5f, __fadd_rn(start, end));

    // pos = o + d*mid  (no FMA)
    const float px = __fadd_rn(ox, __fmul_rn(dx, mid));
    const float py = __fadd_rn(oy, __fmul_rn(dy, mid));
    const float pz = __fadd_rn(oz, __fmul_rn(dz, mid));

    // scale = (pos - aabb0) / (aabb1 - aabb0)
    const float scx = __fdiv_rn(__fsub_rn(px, a0x), __fsub_rn(a1x, a0x));
    const float scy = __fdiv_rn(__fsub_rn(py, a0y), __fsub_rn(a1y, a0y));
    const float scz = __fdiv_rn(__fsub_rn(pz, a0z), __fsub_rn(a1z, a0z));

    const bool inside = (scx >= 0.0f) && (scx < 1.0f) &&
                        (scy >= 0.0f) && (scy < 1.0f) &&
                        (scz >= 0.0f) && (scz < 1.0f);
    const bool geom = inside && (start >= tmin) && (end <= tmax);

    bool valid = false;
    if (geom) {
        int gx = (int)__fmul_rn(scx, (float)GRID_R);
        int gy = (int)__fmul_rn(scy, (float)GRID_R);
        int gz = (int)__fmul_rn(scz, (float)GRID_R);
        gx = min(max(gx, 0), GRID_R - 1);
        gy = min(max(gy, 0), GRID_R - 1);
        gz = min(max(gz, 0), GRID_R - 1);
        const int lin = (gx * GRID_R + gy) * GRID_R + gz;
        bool occv;
        if (mode == 0)      occv = ((const int*)occ)[lin] != 0;
        else if (mode == 1) occv = ((const float*)occ)[lin] != 0.0f;
        else                occv = ((const unsigned char*)occ)[lin] != 0;
        valid = occv;
    }

    // ---- output writes (all elements written every launch) ----
    const int i = (r << 9) | s;
    float* og = out;                                   // origins  [3*NS]
    float* dr = out + 3L * NS;                         // dirs     [3*NS]
    float* sf = out + 6L * NS;                         // s_flat   [NS]
    float* ef = out + 7L * NS;                         // e_flat   [NS]
    float* ri = out + 8L * NS + 2L * N_RAYS;           // ray_indices [NS]
    float* mk = ri + (long)NS;                         // mask     [NS]

    og[3 * i + 0] = valid ? ox : 0.0f;
    og[3 * i + 1] = valid ? oy : 0.0f;
    og[3 * i + 2] = valid ? oz : 0.0f;
    dr[3 * i + 0] = valid ? dx : 0.0f;
    dr[3 * i + 1] = valid ? dy : 0.0f;
    dr[3 * i + 2] = valid ? dz : 0.0f;
    sf[i] = valid ? start : 0.0f;
    ef[i] = valid ? end : 0.0f;
    ri[i] = (float)r;
    mk[i] = valid ? 1.0f : 0.0f;

    // ---- per-ray count: wave ballot + LDS across the 8 waves ----
    const unsigned long long b = __ballot(valid);
    __shared__ int wcount[8];
    if ((threadIdx.x & 63) == 0) wcount[threadIdx.x >> 6] = __popcll(b);
    __syncthreads();
    if (threadIdx.x == 0) {
        int t = 0;
#pragma unroll
        for (int w = 0; w < 8; ++w) t += wcount[w];
        counts[r] = t;
    }
}

// ---------------------------------------------------------------------------
// Kernel 2: exclusive scan of 16384 counts -> packed_info as floats.
// Offsets < 2^24 so float32 is exact.
// ---------------------------------------------------------------------------
__global__ __launch_bounds__(1024)
void scan_kernel(const int* __restrict__ counts, float* __restrict__ packed)
{
    __shared__ int partial[1024];
    const int tid = threadIdx.x;
    const int base = tid * 16;
    int sum = 0;
#pragma unroll
    for (int i = 0; i < 16; ++i) sum += counts[base + i];
    partial[tid] = sum;
    __syncthreads();
    for (int off = 1; off < 1024; off <<= 1) {
        int v = (tid >= off) ? partial[tid - off] : 0;
        __syncthreads();
        partial[tid] += v;
        __syncthreads();
    }
    int run = (tid == 0) ? 0 : partial[tid - 1];
#pragma unroll
    for (int i = 0; i < 16; ++i) {
        const int c = counts[base + i];
        packed[2 * (base + i) + 0] = (float)run;
        packed[2 * (base + i) + 1] = (float)c;
        run += c;
    }
}

extern "C" void kernel_launch(void* const* d_in, const int* in_sizes, int n_in,
                              void* d_out, int out_size, void* d_ws, size_t ws_size,
                              hipStream_t stream) {
    const float* rays_o = (const float*)d_in[0];
    const float* rays_d = (const float*)d_in[1];
    const float* aabb   = (const float*)d_in[2];
    const void*  occ    = d_in[3];
    float* out = (float*)d_out;

    int* flag   = (int*)d_ws;        // 1 int
    int* counts = (int*)d_ws + 16;   // 16384 ints (64B-aligned)

    detect_dtype<<<1, 256, 0, stream>>>(occ, flag);
    sample_kernel<<<N_RAYS, 512, 0, stream>>>(rays_o, rays_d, aabb, occ, flag, out, counts);
    scan_kernel<<<1, 1024, 0, stream>>>(counts, out + 8L * NS);
}

// Round 2
// 353.901 us; speedup vs baseline: 1.0073x; 1.0073x over previous
//
#include <hip/hip_runtime.h>

#define N_RAYS 16384
#define MAX_STEPS 512
#define GRID_R 128
#define N_CELLS (GRID_R * GRID_R * GRID_R) /* 2097152 */
#define NS (N_RAYS * MAX_STEPS)            /* 8388608 samples */

// ws layout (bytes):
//   [0)       flag (1 int)
//   [1024)    counts (16384 ints = 65536 B)
//   [131072)  bit grid (N_CELLS/8 = 262144 B)
#define WS_COUNTS_OFF 1024
#define WS_BITS_OFF 131072
#define WS_NEEDED (WS_BITS_OFF + N_CELLS / 8)

// ---------------------------------------------------------------------------
// Kernel 0: detect occ_grid storage dtype (bool marshalling is ambiguous).
// mode 0 = int32 words (0/1), mode 1 = float32 (0.0/1.0), mode 2 = uint8.
// ---------------------------------------------------------------------------
__global__ void detect_dtype(const void* __restrict__ occ, int* __restrict__ flag) {
    __shared__ int ok_int, ok_flt;
    if (threadIdx.x == 0) { ok_int = 1; ok_flt = 1; }
    __syncthreads();
    const int*   pi = (const int*)occ;
    const float* pf = (const float*)occ;
    for (int i = threadIdx.x; i < 1024; i += blockDim.x) {
        int v = pi[i];
        if (v != 0 && v != 1) atomicAnd(&ok_int, 0);
        float f = pf[i];
        if (!(f == 0.0f || f == 1.0f)) atomicAnd(&ok_flt, 0);
    }
    __syncthreads();
    if (threadIdx.x == 0) flag[0] = ok_int ? 0 : (ok_flt ? 1 : 2);
}

// ---------------------------------------------------------------------------
// Kernel 0.5: compress occ grid -> 1 bit/cell (256 KB, L2-resident everywhere).
// One ballot per wave; lane0 writes the 64-bit mask. Cell c -> bit c of the
// little-endian bit array, so a uint32 read at [c>>5], bit (c&31), works.
// ---------------------------------------------------------------------------
__global__ __launch_bounds__(256)
void pack_occ(const void* __restrict__ occ, const int* __restrict__ flag_p,
              unsigned long long* __restrict__ bits) {
    const int mode = flag_p[0];
    const int idx = blockIdx.x * 256 + threadIdx.x;
    bool v;
    if (mode == 0)      v = ((const int*)occ)[idx] != 0;
    else if (mode == 1) v = ((const float*)occ)[idx] != 0.0f;
    else                v = ((const unsigned char*)occ)[idx] != 0;
    const unsigned long long b = __ballot(v);
    if ((threadIdx.x & 63) == 0) bits[idx >> 6] = b;
}

// ---------------------------------------------------------------------------
// Kernel 1: one block per ray, one thread per step.
// All mul+add chains feeding comparisons use _rn intrinsics (numpy ref = no
// FMA contraction). Outputs staged through a 2 KB LDS mask and written as
// fully-coalesced float4 stores.
// ---------------------------------------------------------------------------
__global__ __launch_bounds__(512)
void sample_kernel(const float* __restrict__ rays_o, const float* __restrict__ rays_d,
                   const float* __restrict__ aabb, const void* __restrict__ occ,
                   const int* __restrict__ flag_p,
                   const unsigned int* __restrict__ bits, int use_bits,
                   float* __restrict__ out, int* __restrict__ counts)
{
    const int r = blockIdx.x;
    const int s = threadIdx.x;

    const float ox = rays_o[3 * r + 0], oy = rays_o[3 * r + 1], oz = rays_o[3 * r + 2];
    const float dx = rays_d[3 * r + 0], dy = rays_d[3 * r + 1], dz = rays_d[3 * r + 2];
    const float a0x = aabb[0], a0y = aabb[1], a0z = aabb[2];
    const float a1x = aabb[3], a1y = aabb[4], a1z = aabb[5];

    // safe_d = where(|d| > 1e-10, d, 1e-10); inv = 1/safe_d (IEEE divide)
    const float sdx = (fabsf(dx) > 1e-10f) ? dx : 1e-10f;
    const float sdy = (fabsf(dy) > 1e-10f) ? dy : 1e-10f;
    const float sdz = (fabsf(dz) > 1e-10f) ? dz : 1e-10f;
    const float invx = __fdiv_rn(1.0f, sdx);
    const float invy = __fdiv_rn(1.0f, sdy);
    const float invz = __fdiv_rn(1.0f, sdz);

    const float t0x = __fmul_rn(__fsub_rn(a0x, ox), invx);
    const float t1x = __fmul_rn(__fsub_rn(a1x, ox), invx);
    const float t0y = __fmul_rn(__fsub_rn(a0y, oy), invy);
    const float t1y = __fmul_rn(__fsub_rn(a1y, oy), invy);
    const float t0z = __fmul_rn(__fsub_rn(a0z, oz), invz);
    const float t1z = __fmul_rn(__fsub_rn(a1z, oz), invz);

    const float tmin = fmaxf(fmaxf(fmaxf(fminf(t0x, t1x), fminf(t0y, t1y)), fminf(t0z, t1z)), 0.05f);
    const float tmax = fminf(fminf(fminf(fmaxf(t0x, t1x), fmaxf(t0y, t1y)), fmaxf(t0z, t1z)), 3.0f);

    const float step_f = (float)((3.0 - 0.05) / 512.0);
    const float start = __fadd_rn(0.05f, __fmul_rn((float)s, step_f));
    const float end   = __fadd_rn(0.05f, __fmul_rn((float)(s + 1), step_f));
    const float mid   = __fmul_rn(0.5f, __fadd_rn(start, end));

    // pos = o + d*mid  (no FMA)
    const float px = __fadd_rn(ox, __fmul_rn(dx, mid));
    const float py = __fadd_rn(oy, __fmul_rn(dy, mid));
    const float pz = __fadd_rn(oz, __fmul_rn(dz, mid));

    // scale = (pos - aabb0) / (aabb1 - aabb0)
    const float scx = __fdiv_rn(__fsub_rn(px, a0x), __fsub_rn(a1x, a0x));
    const float scy = __fdiv_rn(__fsub_rn(py, a0y), __fsub_rn(a1y, a0y));
    const float scz = __fdiv_rn(__fsub_rn(pz, a0z), __fsub_rn(a1z, a0z));

    const bool inside = (scx >= 0.0f) && (scx < 1.0f) &&
                        (scy >= 0.0f) && (scy < 1.0f) &&
                        (scz >= 0.0f) && (scz < 1.0f);
    const bool geom = inside && (start >= tmin) && (end <= tmax);

    bool valid = false;
    if (geom) {
        int gx = (int)__fmul_rn(scx, (float)GRID_R);
        int gy = (int)__fmul_rn(scy, (float)GRID_R);
        int gz = (int)__fmul_rn(scz, (float)GRID_R);
        gx = min(max(gx, 0), GRID_R - 1);
        gy = min(max(gy, 0), GRID_R - 1);
        gz = min(max(gz, 0), GRID_R - 1);
        const int lin = (gx * GRID_R + gy) * GRID_R + gz;
        if (use_bits) {
            valid = (bits[lin >> 5] >> (lin & 31)) & 1u;
        } else {
            const int mode = flag_p[0];
            if (mode == 0)      valid = ((const int*)occ)[lin] != 0;
            else if (mode == 1) valid = ((const float*)occ)[lin] != 0.0f;
            else                valid = ((const unsigned char*)occ)[lin] != 0;
        }
    }

    // ---- per-ray count via ballot, mask to LDS for the vectorized writes ----
    __shared__ float lmask[512];
    __shared__ int wcount[8];
    lmask[s] = valid ? 1.0f : 0.0f;
    const unsigned long long b = __ballot(valid);
    if ((s & 63) == 0) wcount[s >> 6] = __popcll(b);
    __syncthreads();

    // ---- origins & dirs: 384 float4 each per block (interleaved xyz) ----
    if (s < 384) {
        const int f = 4 * s; // float index within this block's 1536-float region
        float4 vo, vd;
#pragma unroll
        for (int k = 0; k < 4; ++k) {
            const int ff = f + k;
            const int smp = ff / 3;          // sample within block
            const int c = ff - smp * 3;      // component
            const float m = lmask[smp];
            const float oc = (c == 0) ? ox : ((c == 1) ? oy : oz);
            const float dc = (c == 0) ? dx : ((c == 1) ? dy : dz);
            ((float*)&vo)[k] = __fmul_rn(m, oc);
            ((float*)&vd)[k] = __fmul_rn(m, dc);
        }
        ((float4*)out)[(long)r * 384 + s] = vo;
        ((float4*)(out + 3L * NS))[(long)r * 384 + s] = vd;
    }

    // ---- s_flat / e_flat / ray_indices / mask: one float4 per thread ----
    {
        const int grp = s >> 7;    // wave-uniform (boundaries at multiples of 64)
        const int t = s & 127;
        float4 v;
#pragma unroll
        for (int k = 0; k < 4; ++k) {
            const int smp = 4 * t + k;
            const float m = lmask[smp];
            float val;
            if (grp == 0)      val = __fmul_rn(m, __fadd_rn(0.05f, __fmul_rn((float)smp, step_f)));
            else if (grp == 1) val = __fmul_rn(m, __fadd_rn(0.05f, __fmul_rn((float)(smp + 1), step_f)));
            else if (grp == 2) val = (float)r;
            else               val = m;
            ((float*)&v)[k] = val;
        }
        float* basep;
        if (grp == 0)      basep = out + 6L * NS;                          // s_flat
        else if (grp == 1) basep = out + 7L * NS;                          // e_flat
        else if (grp == 2) basep = out + 8L * NS + 2L * N_RAYS;            // ray_indices
        else               basep = out + 8L * NS + 2L * N_RAYS + (long)NS; // mask
        ((float4*)basep)[(long)r * 128 + t] = v;
    }

    if (s == 0) {
        int t = 0;
#pragma unroll
        for (int w = 0; w < 8; ++w) t += wcount[w];
        counts[r] = t;
    }
}

// ---------------------------------------------------------------------------
// Kernel 2: exclusive scan of 16384 counts -> packed_info as floats.
// ---------------------------------------------------------------------------
__global__ __launch_bounds__(1024)
void scan_kernel(const int* __restrict__ counts, float* __restrict__ packed)
{
    __shared__ int partial[1024];
    const int tid = threadIdx.x;
    const int base = tid * 16;
    int sum = 0;
#pragma unroll
    for (int i = 0; i < 16; ++i) sum += counts[base + i];
    partial[tid] = sum;
    __syncthreads();
    for (int off = 1; off < 1024; off <<= 1) {
        int v = (tid >= off) ? partial[tid - off] : 0;
        __syncthreads();
        partial[tid] += v;
        __syncthreads();
    }
    int run = (tid == 0) ? 0 : partial[tid - 1];
#pragma unroll
    for (int i = 0; i < 16; ++i) {
        const int c = counts[base + i];
        packed[2 * (base + i) + 0] = (float)run;
        packed[2 * (base + i) + 1] = (float)c;
        run += c;
    }
}

extern "C" void kernel_launch(void* const* d_in, const int* in_sizes, int n_in,
                              void* d_out, int out_size, void* d_ws, size_t ws_size,
                              hipStream_t stream) {
    const float* rays_o = (const float*)d_in[0];
    const float* rays_d = (const float*)d_in[1];
    const float* aabb   = (const float*)d_in[2];
    const void*  occ    = d_in[3];
    float* out = (float*)d_out;

    int* flag   = (int*)d_ws;
    int* counts = (int*)((char*)d_ws + WS_COUNTS_OFF);
    unsigned long long* bits64 = (unsigned long long*)((char*)d_ws + WS_BITS_OFF);
    const int use_bits = (ws_size >= (size_t)WS_NEEDED) ? 1 : 0;

    detect_dtype<<<1, 256, 0, stream>>>(occ, flag);
    if (use_bits)
        pack_occ<<<N_CELLS / 256, 256, 0, stream>>>(occ, flag, bits64);
    sample_kernel<<<N_RAYS, 512, 0, stream>>>(rays_o, rays_d, aabb, occ, flag,
                                              (const unsigned int*)bits64, use_bits,
                                              out, counts);
    scan_kernel<<<1, 1024, 0, stream>>>(counts, out + 8L * NS);
}